// Round 9
// baseline (389.344 us; speedup 1.0000x reference)
//
#include <hip/hip_runtime.h>
#include <cstdint>

#define DI __device__ __forceinline__

// ---- problem constants (N=2e6, spatial=[480,360,32], scales=[2,4,1], 8 batches, sorted) ----
constexpr int NPTS       = 2000000;
constexpr int STRIDE_OUT = 18000001;   // per-scale output stride in int32 elements
constexpr int OFF_INV    = 8000000;
constexpr int OFF_COORS  = 10000000;
constexpr int OFF_NUM    = 18000000;

// scale=2: 240x180x16 ; scale=4: 120x90x8 ; scale=1: 480x360x32
constexpr int R2W  = 172800;    // words; per-batch slice 21600 w
constexpr int R4W  = 21600;     // words; per-batch slice 2700 w
constexpr int R1W  = 1382400;   // words; per-(batch,rho/6) slice 28800 w
constexpr int RW0  = 0;
constexpr int RW1  = R2W;
constexpr int RW2  = R2W + R4W;
constexpr int WTOT = R2W + R4W + R1W;       // 1576800
constexpr int NB1  = (WTOT + 1023) / 1024;  // scan blocks (1540)
constexpr int J2   = 8;                     // copies/chunks for scale-2/4 hist
constexpr int J1   = 4;                     // copies/chunks for scale-1 hist
constexpr int S1W  = 28800;                 // words per scale-1 hist slice
constexpr int S1BITS = S1W * 32;            // 921600 bits per hist slice

// epilogue block partition (inv range padded to multiple of 8 for XCD swizzle)
constexpr int NBLK_INV   = (NPTS + 255) / 256;        // 7813
constexpr int NBLK_INV8  = ((NBLK_INV + 7) / 8) * 8;  // 7816
constexpr int INV_QUOT   = NBLK_INV8 / 8;             // 977
constexpr int NBLK_COORS = (WTOT + 255) / 256;        // 6160
constexpr int NBLK_TAIL  = (3 * NPTS + 255) / 256;    // 23438

// ---- non-temporal stores: keep the 216MB output stream from evicting the 12.6MB
// pairs[] gather working set out of L2 (epilogue) / avoid useless rep allocation (hist).
typedef int  vi4 __attribute__((ext_vector_type(4)));
typedef unsigned int vu4 __attribute__((ext_vector_type(4)));
DI void nt_store_i4(int* p, int4 v) { vi4 x = {v.x, v.y, v.z, v.w}; __builtin_nontemporal_store(x, (vi4*)p); }
DI void nt_store_u4(uint32_t* p, uint4 v) { vu4 x = {v.x, v.y, v.z, v.w}; __builtin_nontemporal_store(x, (vu4*)p); }
DI void nt_store_i(int* p, int v) { __builtin_nontemporal_store(v, p); }

// ---- strict (non-contractible) f32 ops: bit-match XLA's mul,mul,add,sqrt ----
DI float fmul_s(float a, float b){ float r; asm("v_mul_f32 %0, %1, %2" : "=v"(r) : "v"(a), "v"(b)); return r; }
DI float fadd_s(float a, float b){ float r; asm("v_add_f32 %0, %1, %2" : "=v"(r) : "v"(a), "v"(b)); return r; }

// ---- pass 1: per point -> 3 key planes + batch boundary offsets bstart[0..8] ----
__global__ __launch_bounds__(256) void pass_keys(const float4* __restrict__ pts,
                                                 const int* __restrict__ batch, int n,
                                                 int* __restrict__ keys,
                                                 int* __restrict__ bstart) {
  int i = blockIdx.x * 256 + threadIdx.x;
  if (i >= n) return;
  float4 p = pts[i];
  int bi = batch[i];
  const float PI_F     = 3.14159265358979323846f;
  const float TWO_PI_F = 6.28318530717958647692f;
  float rho = sqrtf(fadd_s(fmul_s(p.x, p.x), fmul_s(p.y, p.y)));
  float phi = atan2f(p.y, p.x);
  float tr = (fminf(fmaxf(rho, 0.0f), 50.0f) - 0.0f) / 50.0f;
  float tp = (fminf(fmaxf(phi, -PI_F), PI_F) + PI_F) / TWO_PI_F;
  float tz = (fminf(fmaxf(p.z, -4.0f), 2.0f) + 4.0f) / 6.0f;
  constexpr float C0[3] = {239.f, 119.f, 479.f};
  constexpr float C1[3] = {179.f,  89.f, 359.f};
  constexpr float C2[3] = { 15.f,   7.f,  31.f};
  constexpr int   D0[3] = {240, 120, 480};
  constexpr int   D1[3] = {180,  90, 360};
  constexpr int   D2[3] = { 16,   8,  32};
  #pragma unroll
  for (int s = 0; s < 3; ++s) {
    int a0 = (int)floorf(tr * C0[s]);
    int a1 = (int)floorf(tp * C1[s]);
    int a2 = (int)floorf(tz * C2[s]);
    keys[s * n + i] = ((bi * D0[s] + a0) * D1[s] + a1) * D2[s] + a2;
  }
  // batch is sorted: record boundaries (few threads write; loads are L1/L2-hot)
  if (i == 0) {
    #pragma unroll 1
    for (int k = 0; k <= bi; ++k) bstart[k] = 0;
  }
  int bnext = (i + 1 < n) ? batch[i + 1] : 8;
  #pragma unroll 1
  for (int k = bi + 1; k <= bnext; ++k) bstart[k] = i + 1;
}

// ---- pass 2: fused LDS histograms, EXACTLY 256 blocks (one occupancy wave) ----
// XCD-affine remap (b&7 == batch): fine-slice re-reads of k2 chunks hit XCD-local L2.
// rep copies stored non-temporally (consumed once, usually cross-XCD).
__global__ __launch_bounds__(1024) void hist_all(const int* __restrict__ bstart,
                                                 const int* __restrict__ keys, int n,
                                                 uint32_t* __restrict__ rep2s,
                                                 uint32_t* __restrict__ rep4s,
                                                 uint32_t* __restrict__ rep1s) {
  alignas(16) __shared__ uint32_t bmA[S1W];     // scale-1 slice / scale-2 slice (first 21600)
  alignas(16) __shared__ uint32_t bmB[2700];    // scale-4 slice (2/4 role only)
  int t = threadIdx.x;
  int pb = blockIdx.x;
  if (pb < 64) {
    int bv = pb & 7, j = pb >> 3;               // XCD (pb&7) handles batch bv
    for (int w = t * 4; w < 21600; w += 4096) *reinterpret_cast<uint4*>(bmA + w) = make_uint4(0,0,0,0);
    for (int w = t; w < 2700; w += 1024) bmB[w] = 0;
    __syncthreads();
    int lo = bstart[bv];
    int hi = bstart[bv + 1];
    int sz = hi - lo;
    int s = lo + (int)((long long)sz * j / J2);
    int e = lo + (int)((long long)sz * (j + 1) / J2);
    const int* k0 = keys;
    const int* k1 = keys + n;
    for (int i = s + t; i < e; i += 1024) {
      int ink2 = k0[i] - bv * 691200;   // 240*180*16 bits/batch
      int ink4 = k1[i] - bv * 86400;    // 120*90*8 bits/batch
      atomicOr(&bmA[ink2 >> 5], 1u << (ink2 & 31));
      atomicOr(&bmB[ink4 >> 5], 1u << (ink4 & 31));
    }
    __syncthreads();
    uint32_t* d2 = rep2s + (size_t)j * R2W + bv * 21600;
    uint32_t* d4 = rep4s + (size_t)j * R4W + bv * 2700;
    for (int w = t * 4; w < 21600; w += 4096) nt_store_u4(d2 + w, *reinterpret_cast<uint4*>(bmA + w));
    for (int w = t * 4; w < 2700; w += 4096) nt_store_u4(d4 + w, *reinterpret_cast<uint4*>(bmB + w));
  } else {
    int bv = pb & 7;                    // XCD == batch
    int id = (pb - 64) >> 3;            // [0, 24): (j, r) slot on this XCD
    int j = id / 6, r = id - j * 6;
    int slice = bv * 6 + r;
    for (int w = t * 4; w < S1W; w += 4096) *reinterpret_cast<uint4*>(bmA + w) = make_uint4(0,0,0,0);
    __syncthreads();
    int lo = bstart[bv];
    int hi = bstart[bv + 1];
    int sz = hi - lo;
    int s = lo + (int)((long long)sz * j / J1);
    int e = lo + (int)((long long)sz * (j + 1) / J1);
    const int* k2 = keys + 2 * n;
    int base = bv * 5529600 + r * S1BITS;
    for (int i = s + t; i < e; i += 1024) {
      int rel = k2[i] - base;           // in [0, S1BITS) iff in our rho range
      if ((unsigned)rel < (unsigned)S1BITS) atomicOr(&bmA[rel >> 5], 1u << (rel & 31));
    }
    __syncthreads();
    uint32_t* d = rep1s + (size_t)j * R1W + (size_t)slice * S1W;
    for (int w = t * 4; w < S1W; w += 4096) nt_store_u4(d + w, *reinterpret_cast<uint4*>(bmA + w));
  }
}

// ---- merge copies for a 4-word group at word index `base` ----
DI uint4 merged_words(int base, const uint32_t* __restrict__ rep2s,
                      const uint32_t* __restrict__ rep4s,
                      const uint32_t* __restrict__ rep1s) {
  uint4 acc = make_uint4(0, 0, 0, 0);
  if (base < RW1) {
    #pragma unroll
    for (int c = 0; c < J2; ++c) {
      uint4 w = *reinterpret_cast<const uint4*>(rep2s + (size_t)c * R2W + base);
      acc.x |= w.x; acc.y |= w.y; acc.z |= w.z; acc.w |= w.w;
    }
  } else if (base < RW2) {
    int l = base - RW1;
    #pragma unroll
    for (int c = 0; c < J2; ++c) {
      uint4 w = *reinterpret_cast<const uint4*>(rep4s + (size_t)c * R4W + l);
      acc.x |= w.x; acc.y |= w.y; acc.z |= w.z; acc.w |= w.w;
    }
  } else {
    int l = base - RW2;
    #pragma unroll
    for (int c = 0; c < J1; ++c) {
      uint4 w = *reinterpret_cast<const uint4*>(rep1s + (size_t)c * R1W + l);
      acc.x |= w.x; acc.y |= w.y; acc.z |= w.z; acc.w |= w.w;
    }
  }
  return acc;
}

// ---- pass 3: scanA — merge on the fly, write bits[] + per-block popcount sums ----
__global__ __launch_bounds__(256) void scanA(const uint32_t* __restrict__ rep2s,
                                             const uint32_t* __restrict__ rep4s,
                                             const uint32_t* __restrict__ rep1s,
                                             uint32_t* __restrict__ bits,
                                             uint32_t* __restrict__ blockSums) {
  __shared__ uint32_t lds[256];
  int t = threadIdx.x;
  int base = blockIdx.x * 1024 + t * 4;
  uint32_t s = 0;
  if (base < WTOT) {       // WTOT%4==0; regions 4-aligned
    uint4 m = merged_words(base, rep2s, rep4s, rep1s);
    *reinterpret_cast<uint4*>(bits + base) = m;
    s = __popc(m.x) + __popc(m.y) + __popc(m.z) + __popc(m.w);
  }
  lds[t] = s; __syncthreads();
  for (int off = 128; off > 0; off >>= 1) { if (t < off) lds[t] += lds[t + off]; __syncthreads(); }
  if (t == 0) blockSums[blockIdx.x] = lds[0];
}

// ---- pass 4: scanC — per-word (bits, excl-prefix) pairs ----
__global__ __launch_bounds__(256) void scanC(const uint32_t* __restrict__ bits,
                                             const uint32_t* __restrict__ blockSums,
                                             uint2* __restrict__ pairs) {
  __shared__ uint32_t lds[256];
  int t = threadIdx.x;
  uint32_t bs = 0;
  for (int k = t; k < (int)blockIdx.x; k += 256) bs += blockSums[k];
  lds[t] = bs; __syncthreads();
  for (int off = 128; off > 0; off >>= 1) { if (t < off) lds[t] += lds[t + off]; __syncthreads(); }
  uint32_t blockBase = lds[0];
  __syncthreads();
  int base = blockIdx.x * 1024 + t * 4;
  uint32_t b[4] = {0,0,0,0}; uint32_t c[4]; uint32_t sum = 0;
  if (base < WTOT) {
    uint4 w = *reinterpret_cast<const uint4*>(bits + base);
    b[0] = w.x; b[1] = w.y; b[2] = w.z; b[3] = w.w;
  }
  #pragma unroll
  for (int k = 0; k < 4; ++k) { c[k] = __popc(b[k]); sum += c[k]; }
  lds[t] = sum; __syncthreads();
  for (int off = 1; off < 256; off <<= 1) {
    uint32_t x = (t >= off) ? lds[t - off] : 0u; __syncthreads();
    lds[t] += x; __syncthreads();
  }
  uint32_t excl = lds[t] - sum + blockBase;
  if (base < WTOT) {
    #pragma unroll
    for (int k = 0; k < 4; ++k) { pairs[base + k] = make_uint2(b[k], excl); excl += c[k]; }
  }
}

// ---- exact integer key decode (pow2 masks + magic-mul const division) ----
template <int S>
DI int4 decode_key(int key) {   // returns (b, a0, a1, a2)
  constexpr int D0[3] = {240, 120, 480};
  constexpr int D1[3] = {180,  90, 360};
  constexpr int D2[3] = { 16,   8,  32};
  int a2 = key & (D2[S] - 1);
  int r  = key / D2[S];
  int q  = r / D1[S];
  int a1 = r - q * D1[S];
  int b  = q / D0[S];
  int a0 = q - b * D0[S];
  return make_int4(b, a0, a1, a2);
}

template <int S>
DI void coors_word(int wi_local, uint32_t bits, uint32_t rank, int* __restrict__ coors) {
  int keybase = wi_local * 32;
  while (bits) {
    int j = __builtin_ctz(bits);
    bits &= bits - 1;
    int4 d = decode_key<S>(keybase + j);
    nt_store_i4(coors + (size_t)rank * 4, make_int4(d.x, d.w, d.z, d.y));  // [b,z,phi,rho]
    ++rank;
  }
}

// ---- pass 5: fused epilogue — (bxyz+inv) | coors | tail+num, partitioned by blockIdx.
// inv phase XCD-swizzled; ALL out[] writes non-temporal so the 216MB store stream does
// not evict the pairs[] gather working set (1.6MB/batch, XCD-affine) from L2. ----
__global__ __launch_bounds__(256) void epilogue(int n, const uint2* __restrict__ pairs,
                                                const int* __restrict__ keys,
                                                int* __restrict__ out) {
  int b = blockIdx.x;
  int t = threadIdx.x;
  if (b < NBLK_INV8) {
    // ---- bxyz (decoded from key) + inv (one 8B gather per scale) ----
    int l = (b & 7) * INV_QUOT + (b >> 3);
    if (l >= NBLK_INV) return;
    int i = l * 256 + t;
    if (i >= n) return;
    int key[3] = { keys[i], keys[n + i], keys[2 * n + i] };
    constexpr int RW[3] = {RW0, RW1, RW2};
    nt_store_i4(out + 0 * STRIDE_OUT + (size_t)i * 4, decode_key<0>(key[0]));
    nt_store_i4(out + 1 * STRIDE_OUT + (size_t)i * 4, decode_key<1>(key[1]));
    nt_store_i4(out + 2 * STRIDE_OUT + (size_t)i * 4, decode_key<2>(key[2]));
    #pragma unroll
    for (int s = 0; s < 3; ++s) {
      uint2 pr = pairs[RW[s] + (key[s] >> 5)];
      uint32_t base = pr.y - ((s == 0) ? 0u : pairs[RW[s]].y);
      int rank = (int)(base + __popc(pr.x & ((1u << (key[s] & 31)) - 1u)));
      nt_store_i(out + s * STRIDE_OUT + OFF_INV + i, rank);
    }
  } else if (b < NBLK_INV8 + NBLK_COORS) {
    // ---- coors: one bitmap word per thread, rows in rank order ----
    int wi = (b - NBLK_INV8) * 256 + t;
    if (wi >= WTOT) return;
    uint2 pr = pairs[wi];
    if (!pr.x) return;
    if (wi < RW1)      coors_word<0>(wi,       pr.x, pr.y,                 out + 0 * STRIDE_OUT + OFF_COORS);
    else if (wi < RW2) coors_word<1>(wi - RW1, pr.x, pr.y - pairs[RW1].y,  out + 1 * STRIDE_OUT + OFF_COORS);
    else               coors_word<2>(wi - RW2, pr.x, pr.y - pairs[RW2].y,  out + 2 * STRIDE_OUT + OFF_COORS);
  } else {
    // ---- tail: one int4 row per thread; zero rows [num, n); write num ----
    int idx = (b - NBLK_INV8 - NBLK_COORS) * 256 + t;   // row in [0, 3n)
    if (idx >= 3 * n) return;
    int s = 0, i = idx;
    if (i >= 2 * n)  { s = 2; i -= 2 * n; }
    else if (i >= n) { s = 1; i -= n; }
    uint2 last = pairs[WTOT - 1];
    uint32_t total = last.y + (uint32_t)__popc(last.x);
    uint32_t lo = (s == 0) ? 0u : pairs[(s == 1) ? RW1 : RW2].y;
    uint32_t hi = (s == 0) ? pairs[RW1].y : (s == 1) ? pairs[RW2].y : total;
    uint32_t num = hi - lo;
    if (i == 0) nt_store_i(out + s * STRIDE_OUT + OFF_NUM, (int)num);
    if ((uint32_t)i >= num)
      nt_store_i4(out + s * STRIDE_OUT + OFF_COORS + (size_t)i * 4, make_int4(0, 0, 0, 0));
  }
}

extern "C" void kernel_launch(void* const* d_in, const int* in_sizes, int n_in,
                              void* d_out, int out_size, void* d_ws, size_t ws_size,
                              hipStream_t stream) {
  const float4* pts   = (const float4*)d_in[0];
  const int*    batch = (const int*)d_in[1];
  int n = in_sizes[1];  // 2,000,000
  int* out = (int*)d_out;

  // ws: rep2s | rep4s | rep1s | bits | pairs | blockSums | bstart | keys  (~72 MB, no memsets)
  uint32_t* rep2s     = (uint32_t*)d_ws;
  uint32_t* rep4s     = rep2s + (size_t)J2 * R2W;
  uint32_t* rep1s     = rep4s + (size_t)J2 * R4W;
  uint32_t* bits      = rep1s + (size_t)J1 * R1W;
  uint2*    pairs     = (uint2*)(bits + WTOT);
  uint32_t* blockSums = (uint32_t*)(pairs + WTOT);
  int*      bstart    = (int*)(blockSums + NB1);
  int*      keys      = (int*)(bstart + 16);

  int nblk = (n + 255) / 256;
  pass_keys<<<nblk, 256, 0, stream>>>(pts, batch, n, keys, bstart);
  hist_all<<<256, 1024, 0, stream>>>(bstart, keys, n, rep2s, rep4s, rep1s);
  scanA<<<NB1, 256, 0, stream>>>(rep2s, rep4s, rep1s, bits, blockSums);
  scanC<<<NB1, 256, 0, stream>>>(bits, blockSums, pairs);
  epilogue<<<NBLK_INV8 + NBLK_COORS + NBLK_TAIL, 256, 0, stream>>>(n, pairs, keys, out);
}

// Round 10
// 339.821 us; speedup vs baseline: 1.1457x; 1.1457x over previous
//
#include <hip/hip_runtime.h>
#include <cstdint>

#define DI __device__ __forceinline__

// ---- problem constants (N=2e6, spatial=[480,360,32], scales=[2,4,1], 8 batches, sorted) ----
constexpr int NPTS       = 2000000;
constexpr int STRIDE_OUT = 18000001;   // per-scale output stride in int32 elements
constexpr int OFF_INV    = 8000000;
constexpr int OFF_COORS  = 10000000;
constexpr int OFF_NUM    = 18000000;

// scale=2: 240x180x16 ; scale=4: 120x90x8 ; scale=1: 480x360x32
constexpr int R2W  = 172800;    // words; per-batch slice 21600 w
constexpr int R4W  = 21600;     // words; per-batch slice 2700 w
constexpr int R1W  = 1382400;   // words; per-(batch,rho/6) slice 28800 w
constexpr int RW0  = 0;
constexpr int RW1  = R2W;
constexpr int RW2  = R2W + R4W;
constexpr int WTOT = R2W + R4W + R1W;       // 1576800
constexpr int NB1  = (WTOT + 1023) / 1024;  // scan blocks (1540)
constexpr int J2   = 8;                     // copies/chunks for scale-2/4 hist
constexpr int J1   = 4;                     // copies/chunks for scale-1 hist
constexpr int S1W  = 28800;                 // words per scale-1 hist slice
constexpr int S1BITS = S1W * 32;            // 921600 bits per hist slice

// epilogue block partition (inv range padded to multiple of 8 for XCD swizzle)
constexpr int NBLK_INV   = (NPTS + 255) / 256;        // 7813
constexpr int NBLK_INV8  = ((NBLK_INV + 7) / 8) * 8;  // 7816
constexpr int INV_QUOT   = NBLK_INV8 / 8;             // 977
constexpr int NBLK_COORS = (WTOT + 255) / 256;        // 6160
constexpr int NBLK_TAIL  = (3 * NPTS + 255) / 256;    // 23438

// ---- strict (non-contractible) f32 ops: bit-match XLA's mul,mul,add,sqrt ----
DI float fmul_s(float a, float b){ float r; asm("v_mul_f32 %0, %1, %2" : "=v"(r) : "v"(a), "v"(b)); return r; }
DI float fadd_s(float a, float b){ float r; asm("v_add_f32 %0, %1, %2" : "=v"(r) : "v"(a), "v"(b)); return r; }

// ---- pass 1: per point -> 3 key planes + bxyz rows (exact ints, pre-encode) + bstart.
// bxyz writes live here (BW-idle VALU kernel) to unload the write-heavy epilogue. ----
__global__ __launch_bounds__(256) void pass_keys(const float4* __restrict__ pts,
                                                 const int* __restrict__ batch, int n,
                                                 int* __restrict__ keys,
                                                 int* __restrict__ bstart,
                                                 int* __restrict__ out) {
  int i = blockIdx.x * 256 + threadIdx.x;
  if (i >= n) return;
  float4 p = pts[i];
  int bi = batch[i];
  const float PI_F     = 3.14159265358979323846f;
  const float TWO_PI_F = 6.28318530717958647692f;
  float rho = sqrtf(fadd_s(fmul_s(p.x, p.x), fmul_s(p.y, p.y)));
  float phi = atan2f(p.y, p.x);
  float tr = (fminf(fmaxf(rho, 0.0f), 50.0f) - 0.0f) / 50.0f;
  float tp = (fminf(fmaxf(phi, -PI_F), PI_F) + PI_F) / TWO_PI_F;
  float tz = (fminf(fmaxf(p.z, -4.0f), 2.0f) + 4.0f) / 6.0f;
  constexpr float C0[3] = {239.f, 119.f, 479.f};
  constexpr float C1[3] = {179.f,  89.f, 359.f};
  constexpr float C2[3] = { 15.f,   7.f,  31.f};
  constexpr int   D0[3] = {240, 120, 480};
  constexpr int   D1[3] = {180,  90, 360};
  constexpr int   D2[3] = { 16,   8,  32};
  #pragma unroll
  for (int s = 0; s < 3; ++s) {
    int a0 = (int)floorf(tr * C0[s]);
    int a1 = (int)floorf(tp * C1[s]);
    int a2 = (int)floorf(tz * C2[s]);
    keys[s * n + i] = ((bi * D0[s] + a0) * D1[s] + a1) * D2[s] + a2;
    *reinterpret_cast<int4*>(out + s * STRIDE_OUT + (size_t)i * 4) = make_int4(bi, a0, a1, a2);
  }
  // batch is sorted: record boundaries (few threads write; loads are L1/L2-hot)
  if (i == 0) {
    #pragma unroll 1
    for (int k = 0; k <= bi; ++k) bstart[k] = 0;
  }
  int bnext = (i + 1 < n) ? batch[i + 1] : 8;
  #pragma unroll 1
  for (int k = bi + 1; k <= bnext; ++k) bstart[k] = i + 1;
}

// ---- pass 2: fused LDS histograms, EXACTLY 256 blocks (one occupancy wave) ----
// XCD-affine remap (b&7 == batch): fine-slice re-reads of k2 chunks hit XCD-local L2.
__global__ __launch_bounds__(1024) void hist_all(const int* __restrict__ bstart,
                                                 const int* __restrict__ keys, int n,
                                                 uint32_t* __restrict__ rep2s,
                                                 uint32_t* __restrict__ rep4s,
                                                 uint32_t* __restrict__ rep1s) {
  alignas(16) __shared__ uint32_t bmA[S1W];     // scale-1 slice / scale-2 slice (first 21600)
  alignas(16) __shared__ uint32_t bmB[2700];    // scale-4 slice (2/4 role only)
  int t = threadIdx.x;
  int pb = blockIdx.x;
  if (pb < 64) {
    int bv = pb & 7, j = pb >> 3;               // XCD (pb&7) handles batch bv
    for (int w = t * 4; w < 21600; w += 4096) *reinterpret_cast<uint4*>(bmA + w) = make_uint4(0,0,0,0);
    for (int w = t; w < 2700; w += 1024) bmB[w] = 0;
    __syncthreads();
    int lo = bstart[bv];
    int hi = bstart[bv + 1];
    int sz = hi - lo;
    int s = lo + (int)((long long)sz * j / J2);
    int e = lo + (int)((long long)sz * (j + 1) / J2);
    const int* k0 = keys;
    const int* k1 = keys + n;
    for (int i = s + t; i < e; i += 1024) {
      int ink2 = k0[i] - bv * 691200;   // 240*180*16 bits/batch
      int ink4 = k1[i] - bv * 86400;    // 120*90*8 bits/batch
      atomicOr(&bmA[ink2 >> 5], 1u << (ink2 & 31));
      atomicOr(&bmB[ink4 >> 5], 1u << (ink4 & 31));
    }
    __syncthreads();
    uint32_t* d2 = rep2s + (size_t)j * R2W + bv * 21600;
    uint32_t* d4 = rep4s + (size_t)j * R4W + bv * 2700;
    for (int w = t * 4; w < 21600; w += 4096) *reinterpret_cast<uint4*>(d2 + w) = *reinterpret_cast<uint4*>(bmA + w);
    for (int w = t * 4; w < 2700; w += 4096) *reinterpret_cast<uint4*>(d4 + w) = *reinterpret_cast<uint4*>(bmB + w);
  } else {
    int bv = pb & 7;                    // XCD == batch
    int id = (pb - 64) >> 3;            // [0, 24): (j, r) slot on this XCD
    int j = id / 6, r = id - j * 6;
    int slice = bv * 6 + r;
    for (int w = t * 4; w < S1W; w += 4096) *reinterpret_cast<uint4*>(bmA + w) = make_uint4(0,0,0,0);
    __syncthreads();
    int lo = bstart[bv];
    int hi = bstart[bv + 1];
    int sz = hi - lo;
    int s = lo + (int)((long long)sz * j / J1);
    int e = lo + (int)((long long)sz * (j + 1) / J1);
    const int* k2 = keys + 2 * n;
    int base = bv * 5529600 + r * S1BITS;
    for (int i = s + t; i < e; i += 1024) {
      int rel = k2[i] - base;           // in [0, S1BITS) iff in our rho range
      if ((unsigned)rel < (unsigned)S1BITS) atomicOr(&bmA[rel >> 5], 1u << (rel & 31));
    }
    __syncthreads();
    uint32_t* d = rep1s + (size_t)j * R1W + (size_t)slice * S1W;
    for (int w = t * 4; w < S1W; w += 4096) *reinterpret_cast<uint4*>(d + w) = *reinterpret_cast<uint4*>(bmA + w);
  }
}

// ---- merge copies for a 4-word group at word index `base` ----
DI uint4 merged_words(int base, const uint32_t* __restrict__ rep2s,
                      const uint32_t* __restrict__ rep4s,
                      const uint32_t* __restrict__ rep1s) {
  uint4 acc = make_uint4(0, 0, 0, 0);
  if (base < RW1) {
    #pragma unroll
    for (int c = 0; c < J2; ++c) {
      uint4 w = *reinterpret_cast<const uint4*>(rep2s + (size_t)c * R2W + base);
      acc.x |= w.x; acc.y |= w.y; acc.z |= w.z; acc.w |= w.w;
    }
  } else if (base < RW2) {
    int l = base - RW1;
    #pragma unroll
    for (int c = 0; c < J2; ++c) {
      uint4 w = *reinterpret_cast<const uint4*>(rep4s + (size_t)c * R4W + l);
      acc.x |= w.x; acc.y |= w.y; acc.z |= w.z; acc.w |= w.w;
    }
  } else {
    int l = base - RW2;
    #pragma unroll
    for (int c = 0; c < J1; ++c) {
      uint4 w = *reinterpret_cast<const uint4*>(rep1s + (size_t)c * R1W + l);
      acc.x |= w.x; acc.y |= w.y; acc.z |= w.z; acc.w |= w.w;
    }
  }
  return acc;
}

// ---- pass 3: scanA — merge on the fly, write bits[] + per-block popcount sums ----
__global__ __launch_bounds__(256) void scanA(const uint32_t* __restrict__ rep2s,
                                             const uint32_t* __restrict__ rep4s,
                                             const uint32_t* __restrict__ rep1s,
                                             uint32_t* __restrict__ bits,
                                             uint32_t* __restrict__ blockSums) {
  __shared__ uint32_t lds[256];
  int t = threadIdx.x;
  int base = blockIdx.x * 1024 + t * 4;
  uint32_t s = 0;
  if (base < WTOT) {       // WTOT%4==0; regions 4-aligned
    uint4 m = merged_words(base, rep2s, rep4s, rep1s);
    *reinterpret_cast<uint4*>(bits + base) = m;
    s = __popc(m.x) + __popc(m.y) + __popc(m.z) + __popc(m.w);
  }
  lds[t] = s; __syncthreads();
  for (int off = 128; off > 0; off >>= 1) { if (t < off) lds[t] += lds[t + off]; __syncthreads(); }
  if (t == 0) blockSums[blockIdx.x] = lds[0];
}

// ---- pass 4: scanC — per-word (bits, excl-prefix) pairs ----
__global__ __launch_bounds__(256) void scanC(const uint32_t* __restrict__ bits,
                                             const uint32_t* __restrict__ blockSums,
                                             uint2* __restrict__ pairs) {
  __shared__ uint32_t lds[256];
  int t = threadIdx.x;
  uint32_t bs = 0;
  for (int k = t; k < (int)blockIdx.x; k += 256) bs += blockSums[k];
  lds[t] = bs; __syncthreads();
  for (int off = 128; off > 0; off >>= 1) { if (t < off) lds[t] += lds[t + off]; __syncthreads(); }
  uint32_t blockBase = lds[0];
  __syncthreads();
  int base = blockIdx.x * 1024 + t * 4;
  uint32_t b[4] = {0,0,0,0}; uint32_t c[4]; uint32_t sum = 0;
  if (base < WTOT) {
    uint4 w = *reinterpret_cast<const uint4*>(bits + base);
    b[0] = w.x; b[1] = w.y; b[2] = w.z; b[3] = w.w;
  }
  #pragma unroll
  for (int k = 0; k < 4; ++k) { c[k] = __popc(b[k]); sum += c[k]; }
  lds[t] = sum; __syncthreads();
  for (int off = 1; off < 256; off <<= 1) {
    uint32_t x = (t >= off) ? lds[t - off] : 0u; __syncthreads();
    lds[t] += x; __syncthreads();
  }
  uint32_t excl = lds[t] - sum + blockBase;
  if (base < WTOT) {
    #pragma unroll
    for (int k = 0; k < 4; ++k) { pairs[base + k] = make_uint2(b[k], excl); excl += c[k]; }
  }
}

// ---- exact integer key decode (pow2 masks + magic-mul const division) ----
template <int S>
DI int4 decode_key(int key) {   // returns (b, a0, a1, a2)
  constexpr int D0[3] = {240, 120, 480};
  constexpr int D1[3] = {180,  90, 360};
  constexpr int D2[3] = { 16,   8,  32};
  int a2 = key & (D2[S] - 1);
  int r  = key / D2[S];
  int q  = r / D1[S];
  int a1 = r - q * D1[S];
  int b  = q / D0[S];
  int a0 = q - b * D0[S];
  return make_int4(b, a0, a1, a2);
}

template <int S>
DI void coors_word(int wi_local, uint32_t bits, uint32_t rank, int* __restrict__ coors) {
  int keybase = wi_local * 32;
  while (bits) {
    int j = __builtin_ctz(bits);
    bits &= bits - 1;
    int4 d = decode_key<S>(keybase + j);
    *reinterpret_cast<int4*>(coors + (size_t)rank * 4) = make_int4(d.x, d.w, d.z, d.y);  // [b,z,phi,rho]
    ++rank;
  }
}

// ---- pass 5: fused epilogue — inv | coors | tail+num (bxyz moved to pass_keys).
// inv phase XCD-swizzled ((b&7)*INV_QUOT + b>>3) for per-batch pairs L2 affinity. ----
__global__ __launch_bounds__(256) void epilogue(int n, const uint2* __restrict__ pairs,
                                                const int* __restrict__ keys,
                                                int* __restrict__ out) {
  int b = blockIdx.x;
  int t = threadIdx.x;
  if (b < NBLK_INV8) {
    // ---- inv: one 8B gather per scale ----
    int l = (b & 7) * INV_QUOT + (b >> 3);
    if (l >= NBLK_INV) return;
    int i = l * 256 + t;
    if (i >= n) return;
    int key[3] = { keys[i], keys[n + i], keys[2 * n + i] };
    constexpr int RW[3] = {RW0, RW1, RW2};
    #pragma unroll
    for (int s = 0; s < 3; ++s) {
      uint2 pr = pairs[RW[s] + (key[s] >> 5)];
      uint32_t base = pr.y - ((s == 0) ? 0u : pairs[RW[s]].y);
      int rank = (int)(base + __popc(pr.x & ((1u << (key[s] & 31)) - 1u)));
      out[s * STRIDE_OUT + OFF_INV + i] = rank;
    }
  } else if (b < NBLK_INV8 + NBLK_COORS) {
    // ---- coors: one bitmap word per thread, rows in rank order ----
    int wi = (b - NBLK_INV8) * 256 + t;
    if (wi >= WTOT) return;
    uint2 pr = pairs[wi];
    if (!pr.x) return;
    if (wi < RW1)      coors_word<0>(wi,       pr.x, pr.y,                 out + 0 * STRIDE_OUT + OFF_COORS);
    else if (wi < RW2) coors_word<1>(wi - RW1, pr.x, pr.y - pairs[RW1].y,  out + 1 * STRIDE_OUT + OFF_COORS);
    else               coors_word<2>(wi - RW2, pr.x, pr.y - pairs[RW2].y,  out + 2 * STRIDE_OUT + OFF_COORS);
  } else {
    // ---- tail: one int4 row per thread; zero rows [num, n); write num ----
    int idx = (b - NBLK_INV8 - NBLK_COORS) * 256 + t;   // row in [0, 3n)
    if (idx >= 3 * n) return;
    int s = 0, i = idx;
    if (i >= 2 * n)  { s = 2; i -= 2 * n; }
    else if (i >= n) { s = 1; i -= n; }
    uint2 last = pairs[WTOT - 1];
    uint32_t total = last.y + (uint32_t)__popc(last.x);
    uint32_t lo = (s == 0) ? 0u : pairs[(s == 1) ? RW1 : RW2].y;
    uint32_t hi = (s == 0) ? pairs[RW1].y : (s == 1) ? pairs[RW2].y : total;
    uint32_t num = hi - lo;
    if (i == 0) out[s * STRIDE_OUT + OFF_NUM] = (int)num;
    if ((uint32_t)i >= num)
      *reinterpret_cast<int4*>(out + s * STRIDE_OUT + OFF_COORS + (size_t)i * 4) = make_int4(0, 0, 0, 0);
  }
}

extern "C" void kernel_launch(void* const* d_in, const int* in_sizes, int n_in,
                              void* d_out, int out_size, void* d_ws, size_t ws_size,
                              hipStream_t stream) {
  const float4* pts   = (const float4*)d_in[0];
  const int*    batch = (const int*)d_in[1];
  int n = in_sizes[1];  // 2,000,000
  int* out = (int*)d_out;

  // ws: rep2s | rep4s | rep1s | bits | pairs | blockSums | bstart | keys  (~72 MB, no memsets)
  uint32_t* rep2s     = (uint32_t*)d_ws;
  uint32_t* rep4s     = rep2s + (size_t)J2 * R2W;
  uint32_t* rep1s     = rep4s + (size_t)J2 * R4W;
  uint32_t* bits      = rep1s + (size_t)J1 * R1W;
  uint2*    pairs     = (uint2*)(bits + WTOT);
  uint32_t* blockSums = (uint32_t*)(pairs + WTOT);
  int*      bstart    = (int*)(blockSums + NB1);
  int*      keys      = (int*)(bstart + 16);

  int nblk = (n + 255) / 256;
  pass_keys<<<nblk, 256, 0, stream>>>(pts, batch, n, keys, bstart, out);
  hist_all<<<256, 1024, 0, stream>>>(bstart, keys, n, rep2s, rep4s, rep1s);
  scanA<<<NB1, 256, 0, stream>>>(rep2s, rep4s, rep1s, bits, blockSums);
  scanC<<<NB1, 256, 0, stream>>>(bits, blockSums, pairs);
  epilogue<<<NBLK_INV8 + NBLK_COORS + NBLK_TAIL, 256, 0, stream>>>(n, pairs, keys, out);
}

// Round 11
// 326.392 us; speedup vs baseline: 1.1929x; 1.0411x over previous
//
#include <hip/hip_runtime.h>
#include <cstdint>

#define DI __device__ __forceinline__

// ---- problem constants (N=2e6, spatial=[480,360,32], scales=[2,4,1], 8 batches, sorted) ----
constexpr int NPTS       = 2000000;
constexpr int STRIDE_OUT = 18000001;   // per-scale output stride in int32 elements
constexpr int OFF_INV    = 8000000;
constexpr int OFF_COORS  = 10000000;
constexpr int OFF_NUM    = 18000000;

// scale=2: 240x180x16 ; scale=4: 120x90x8 ; scale=1: 480x360x32
constexpr int R2W  = 172800;    // words; per-batch slice 21600 w
constexpr int R4W  = 21600;     // words; per-batch slice 2700 w
constexpr int R1W  = 1382400;   // words; per-(batch,rho/6) slice 28800 w
constexpr int RW0  = 0;
constexpr int RW1  = R2W;
constexpr int RW2  = R2W + R4W;
constexpr int WTOT = R2W + R4W + R1W;       // 1576800
constexpr int NB1  = (WTOT + 1023) / 1024;  // scan blocks (1540)
constexpr int J2   = 8;                     // copies/chunks for scale-2/4 hist
constexpr int J1   = 4;                     // copies/chunks for scale-1 hist
constexpr int S1W  = 28800;                 // words per scale-1 hist slice
constexpr int S1BITS = S1W * 32;            // 921600 bits per hist slice

// epilogue block partition (inv range padded to multiple of 8 for XCD swizzle)
constexpr int NBLK_INV   = (NPTS + 255) / 256;        // 7813
constexpr int NBLK_INV8  = ((NBLK_INV + 7) / 8) * 8;  // 7816
constexpr int INV_QUOT   = NBLK_INV8 / 8;             // 977
constexpr int NBLK_COORS = (WTOT + 255) / 256;        // 6160
constexpr int NBLK_TAIL  = (3 * NPTS + 255) / 256;    // 23438

// ---- strict (non-contractible) f32 ops: bit-match XLA's mul,mul,add,sqrt ----
DI float fmul_s(float a, float b){ float r; asm("v_mul_f32 %0, %1, %2" : "=v"(r) : "v"(a), "v"(b)); return r; }
DI float fadd_s(float a, float b){ float r; asm("v_add_f32 %0, %1, %2" : "=v"(r) : "v"(a), "v"(b)); return r; }

// ---- pass 1: per point -> 3 key planes + batch boundary offsets bstart[0..8] ----
__global__ __launch_bounds__(256) void pass_keys(const float4* __restrict__ pts,
                                                 const int* __restrict__ batch, int n,
                                                 int* __restrict__ keys,
                                                 int* __restrict__ bstart) {
  int i = blockIdx.x * 256 + threadIdx.x;
  if (i >= n) return;
  float4 p = pts[i];
  int bi = batch[i];
  const float PI_F     = 3.14159265358979323846f;
  const float TWO_PI_F = 6.28318530717958647692f;
  float rho = sqrtf(fadd_s(fmul_s(p.x, p.x), fmul_s(p.y, p.y)));
  float phi = atan2f(p.y, p.x);
  float tr = (fminf(fmaxf(rho, 0.0f), 50.0f) - 0.0f) / 50.0f;
  float tp = (fminf(fmaxf(phi, -PI_F), PI_F) + PI_F) / TWO_PI_F;
  float tz = (fminf(fmaxf(p.z, -4.0f), 2.0f) + 4.0f) / 6.0f;
  constexpr float C0[3] = {239.f, 119.f, 479.f};
  constexpr float C1[3] = {179.f,  89.f, 359.f};
  constexpr float C2[3] = { 15.f,   7.f,  31.f};
  constexpr int   D0[3] = {240, 120, 480};
  constexpr int   D1[3] = {180,  90, 360};
  constexpr int   D2[3] = { 16,   8,  32};
  #pragma unroll
  for (int s = 0; s < 3; ++s) {
    int a0 = (int)floorf(tr * C0[s]);
    int a1 = (int)floorf(tp * C1[s]);
    int a2 = (int)floorf(tz * C2[s]);
    keys[s * n + i] = ((bi * D0[s] + a0) * D1[s] + a1) * D2[s] + a2;
  }
  // batch is sorted: record boundaries (few threads write; loads are L1/L2-hot)
  if (i == 0) {
    #pragma unroll 1
    for (int k = 0; k <= bi; ++k) bstart[k] = 0;
  }
  int bnext = (i + 1 < n) ? batch[i + 1] : 8;
  #pragma unroll 1
  for (int k = bi + 1; k <= bnext; ++k) bstart[k] = i + 1;
}

// ---- pass 2: fused LDS histograms, EXACTLY 256 blocks (one occupancy wave) ----
// XCD-affine remap (b&7 == batch): fine-slice re-reads of k2 chunks hit XCD-local L2.
__global__ __launch_bounds__(1024) void hist_all(const int* __restrict__ bstart,
                                                 const int* __restrict__ keys, int n,
                                                 uint32_t* __restrict__ rep2s,
                                                 uint32_t* __restrict__ rep4s,
                                                 uint32_t* __restrict__ rep1s) {
  alignas(16) __shared__ uint32_t bmA[S1W];     // scale-1 slice / scale-2 slice (first 21600)
  alignas(16) __shared__ uint32_t bmB[2700];    // scale-4 slice (2/4 role only)
  int t = threadIdx.x;
  int pb = blockIdx.x;
  if (pb < 64) {
    int bv = pb & 7, j = pb >> 3;               // XCD (pb&7) handles batch bv
    for (int w = t * 4; w < 21600; w += 4096) *reinterpret_cast<uint4*>(bmA + w) = make_uint4(0,0,0,0);
    for (int w = t; w < 2700; w += 1024) bmB[w] = 0;
    __syncthreads();
    int lo = bstart[bv];
    int hi = bstart[bv + 1];
    int sz = hi - lo;
    int s = lo + (int)((long long)sz * j / J2);
    int e = lo + (int)((long long)sz * (j + 1) / J2);
    const int* k0 = keys;
    const int* k1 = keys + n;
    for (int i = s + t; i < e; i += 1024) {
      int ink2 = k0[i] - bv * 691200;   // 240*180*16 bits/batch
      int ink4 = k1[i] - bv * 86400;    // 120*90*8 bits/batch
      atomicOr(&bmA[ink2 >> 5], 1u << (ink2 & 31));
      atomicOr(&bmB[ink4 >> 5], 1u << (ink4 & 31));
    }
    __syncthreads();
    uint32_t* d2 = rep2s + (size_t)j * R2W + bv * 21600;
    uint32_t* d4 = rep4s + (size_t)j * R4W + bv * 2700;
    for (int w = t * 4; w < 21600; w += 4096) *reinterpret_cast<uint4*>(d2 + w) = *reinterpret_cast<uint4*>(bmA + w);
    for (int w = t * 4; w < 2700; w += 4096) *reinterpret_cast<uint4*>(d4 + w) = *reinterpret_cast<uint4*>(bmB + w);
  } else {
    int bv = pb & 7;                    // XCD == batch
    int id = (pb - 64) >> 3;            // [0, 24): (j, r) slot on this XCD
    int j = id / 6, r = id - j * 6;
    int slice = bv * 6 + r;
    for (int w = t * 4; w < S1W; w += 4096) *reinterpret_cast<uint4*>(bmA + w) = make_uint4(0,0,0,0);
    __syncthreads();
    int lo = bstart[bv];
    int hi = bstart[bv + 1];
    int sz = hi - lo;
    int s = lo + (int)((long long)sz * j / J1);
    int e = lo + (int)((long long)sz * (j + 1) / J1);
    const int* k2 = keys + 2 * n;
    int base = bv * 5529600 + r * S1BITS;
    for (int i = s + t; i < e; i += 1024) {
      int rel = k2[i] - base;           // in [0, S1BITS) iff in our rho range
      if ((unsigned)rel < (unsigned)S1BITS) atomicOr(&bmA[rel >> 5], 1u << (rel & 31));
    }
    __syncthreads();
    uint32_t* d = rep1s + (size_t)j * R1W + (size_t)slice * S1W;
    for (int w = t * 4; w < S1W; w += 4096) *reinterpret_cast<uint4*>(d + w) = *reinterpret_cast<uint4*>(bmA + w);
  }
}

// ---- merge copies for a 4-word group at word index `base` ----
DI uint4 merged_words(int base, const uint32_t* __restrict__ rep2s,
                      const uint32_t* __restrict__ rep4s,
                      const uint32_t* __restrict__ rep1s) {
  uint4 acc = make_uint4(0, 0, 0, 0);
  if (base < RW1) {
    #pragma unroll
    for (int c = 0; c < J2; ++c) {
      uint4 w = *reinterpret_cast<const uint4*>(rep2s + (size_t)c * R2W + base);
      acc.x |= w.x; acc.y |= w.y; acc.z |= w.z; acc.w |= w.w;
    }
  } else if (base < RW2) {
    int l = base - RW1;
    #pragma unroll
    for (int c = 0; c < J2; ++c) {
      uint4 w = *reinterpret_cast<const uint4*>(rep4s + (size_t)c * R4W + l);
      acc.x |= w.x; acc.y |= w.y; acc.z |= w.z; acc.w |= w.w;
    }
  } else {
    int l = base - RW2;
    #pragma unroll
    for (int c = 0; c < J1; ++c) {
      uint4 w = *reinterpret_cast<const uint4*>(rep1s + (size_t)c * R1W + l);
      acc.x |= w.x; acc.y |= w.y; acc.z |= w.z; acc.w |= w.w;
    }
  }
  return acc;
}

// ---- pass 3: scanA — merge on the fly, write bits[] + per-block popcount sums ----
__global__ __launch_bounds__(256) void scanA(const uint32_t* __restrict__ rep2s,
                                             const uint32_t* __restrict__ rep4s,
                                             const uint32_t* __restrict__ rep1s,
                                             uint32_t* __restrict__ bits,
                                             uint32_t* __restrict__ blockSums) {
  __shared__ uint32_t lds[256];
  int t = threadIdx.x;
  int base = blockIdx.x * 1024 + t * 4;
  uint32_t s = 0;
  if (base < WTOT) {       // WTOT%4==0; regions 4-aligned
    uint4 m = merged_words(base, rep2s, rep4s, rep1s);
    *reinterpret_cast<uint4*>(bits + base) = m;
    s = __popc(m.x) + __popc(m.y) + __popc(m.z) + __popc(m.w);
  }
  lds[t] = s; __syncthreads();
  for (int off = 128; off > 0; off >>= 1) { if (t < off) lds[t] += lds[t + off]; __syncthreads(); }
  if (t == 0) blockSums[blockIdx.x] = lds[0];
}

// ---- pass 4: scanC — per-word (bits, excl-prefix) pairs; each block sums its own base
// from blockSums[0..b) (L2-broadcast, <=6KB) -> no separate scanB launch. ----
__global__ __launch_bounds__(256) void scanC(const uint32_t* __restrict__ bits,
                                             const uint32_t* __restrict__ blockSums,
                                             uint2* __restrict__ pairs) {
  __shared__ uint32_t lds[256];
  int t = threadIdx.x;
  uint32_t bs = 0;
  for (int k = t; k < (int)blockIdx.x; k += 256) bs += blockSums[k];
  lds[t] = bs; __syncthreads();
  for (int off = 128; off > 0; off >>= 1) { if (t < off) lds[t] += lds[t + off]; __syncthreads(); }
  uint32_t blockBase = lds[0];
  __syncthreads();
  int base = blockIdx.x * 1024 + t * 4;
  uint32_t b[4] = {0,0,0,0}; uint32_t c[4]; uint32_t sum = 0;
  if (base < WTOT) {
    uint4 w = *reinterpret_cast<const uint4*>(bits + base);
    b[0] = w.x; b[1] = w.y; b[2] = w.z; b[3] = w.w;
  }
  #pragma unroll
  for (int k = 0; k < 4; ++k) { c[k] = __popc(b[k]); sum += c[k]; }
  lds[t] = sum; __syncthreads();
  for (int off = 1; off < 256; off <<= 1) {
    uint32_t x = (t >= off) ? lds[t - off] : 0u; __syncthreads();
    lds[t] += x; __syncthreads();
  }
  uint32_t excl = lds[t] - sum + blockBase;
  if (base < WTOT) {
    #pragma unroll
    for (int k = 0; k < 4; ++k) { pairs[base + k] = make_uint2(b[k], excl); excl += c[k]; }
  }
}

// ---- exact integer key decode (pow2 masks + magic-mul const division) ----
template <int S>
DI int4 decode_key(int key) {   // returns (b, a0, a1, a2)
  constexpr int D0[3] = {240, 120, 480};
  constexpr int D1[3] = {180,  90, 360};
  constexpr int D2[3] = { 16,   8,  32};
  int a2 = key & (D2[S] - 1);
  int r  = key / D2[S];
  int q  = r / D1[S];
  int a1 = r - q * D1[S];
  int b  = q / D0[S];
  int a0 = q - b * D0[S];
  return make_int4(b, a0, a1, a2);
}

template <int S>
DI void coors_word(int wi_local, uint32_t bits, uint32_t rank, int* __restrict__ coors) {
  int keybase = wi_local * 32;
  while (bits) {
    int j = __builtin_ctz(bits);
    bits &= bits - 1;
    int4 d = decode_key<S>(keybase + j);
    *reinterpret_cast<int4*>(coors + (size_t)rank * 4) = make_int4(d.x, d.w, d.z, d.y);  // [b,z,phi,rho]
    ++rank;
  }
}

// ---- pass 5: fused epilogue — (bxyz+inv) | coors | tail+num, partitioned by blockIdx.
// inv phase XCD-swizzled ((b&7)*INV_QUOT + b>>3): per-batch pairs gathers (1.6MB/batch)
// stay XCD-L2-affine, and the bxyz streaming stores overlap the gather latency (moving
// them out measured +12us — R10). Disjoint d_out regions -> race-free. ----
__global__ __launch_bounds__(256) void epilogue(int n, const uint2* __restrict__ pairs,
                                                const int* __restrict__ keys,
                                                int* __restrict__ out) {
  int b = blockIdx.x;
  int t = threadIdx.x;
  if (b < NBLK_INV8) {
    // ---- bxyz (decoded from key) + inv (one 8B gather per scale) ----
    int l = (b & 7) * INV_QUOT + (b >> 3);
    if (l >= NBLK_INV) return;
    int i = l * 256 + t;
    if (i >= n) return;
    int key[3] = { keys[i], keys[n + i], keys[2 * n + i] };
    constexpr int RW[3] = {RW0, RW1, RW2};
    *reinterpret_cast<int4*>(out + 0 * STRIDE_OUT + (size_t)i * 4) = decode_key<0>(key[0]);
    *reinterpret_cast<int4*>(out + 1 * STRIDE_OUT + (size_t)i * 4) = decode_key<1>(key[1]);
    *reinterpret_cast<int4*>(out + 2 * STRIDE_OUT + (size_t)i * 4) = decode_key<2>(key[2]);
    #pragma unroll
    for (int s = 0; s < 3; ++s) {
      uint2 pr = pairs[RW[s] + (key[s] >> 5)];
      uint32_t base = pr.y - ((s == 0) ? 0u : pairs[RW[s]].y);
      int rank = (int)(base + __popc(pr.x & ((1u << (key[s] & 31)) - 1u)));
      out[s * STRIDE_OUT + OFF_INV + i] = rank;
    }
  } else if (b < NBLK_INV8 + NBLK_COORS) {
    // ---- coors: one bitmap word per thread, rows in rank order ----
    int wi = (b - NBLK_INV8) * 256 + t;
    if (wi >= WTOT) return;
    uint2 pr = pairs[wi];
    if (!pr.x) return;
    if (wi < RW1)      coors_word<0>(wi,       pr.x, pr.y,                 out + 0 * STRIDE_OUT + OFF_COORS);
    else if (wi < RW2) coors_word<1>(wi - RW1, pr.x, pr.y - pairs[RW1].y,  out + 1 * STRIDE_OUT + OFF_COORS);
    else               coors_word<2>(wi - RW2, pr.x, pr.y - pairs[RW2].y,  out + 2 * STRIDE_OUT + OFF_COORS);
  } else {
    // ---- tail: one int4 row per thread; zero rows [num, n); write num ----
    int idx = (b - NBLK_INV8 - NBLK_COORS) * 256 + t;   // row in [0, 3n)
    if (idx >= 3 * n) return;
    int s = 0, i = idx;
    if (i >= 2 * n)  { s = 2; i -= 2 * n; }
    else if (i >= n) { s = 1; i -= n; }
    uint2 last = pairs[WTOT - 1];
    uint32_t total = last.y + (uint32_t)__popc(last.x);
    uint32_t lo = (s == 0) ? 0u : pairs[(s == 1) ? RW1 : RW2].y;
    uint32_t hi = (s == 0) ? pairs[RW1].y : (s == 1) ? pairs[RW2].y : total;
    uint32_t num = hi - lo;
    if (i == 0) out[s * STRIDE_OUT + OFF_NUM] = (int)num;
    if ((uint32_t)i >= num)
      *reinterpret_cast<int4*>(out + s * STRIDE_OUT + OFF_COORS + (size_t)i * 4) = make_int4(0, 0, 0, 0);
  }
}

extern "C" void kernel_launch(void* const* d_in, const int* in_sizes, int n_in,
                              void* d_out, int out_size, void* d_ws, size_t ws_size,
                              hipStream_t stream) {
  const float4* pts   = (const float4*)d_in[0];
  const int*    batch = (const int*)d_in[1];
  int n = in_sizes[1];  // 2,000,000
  int* out = (int*)d_out;

  // ws: rep2s | rep4s | rep1s | bits | pairs | blockSums | bstart | keys  (~72 MB, no memsets)
  uint32_t* rep2s     = (uint32_t*)d_ws;
  uint32_t* rep4s     = rep2s + (size_t)J2 * R2W;
  uint32_t* rep1s     = rep4s + (size_t)J2 * R4W;
  uint32_t* bits      = rep1s + (size_t)J1 * R1W;
  uint2*    pairs     = (uint2*)(bits + WTOT);
  uint32_t* blockSums = (uint32_t*)(pairs + WTOT);
  int*      bstart    = (int*)(blockSums + NB1);
  int*      keys      = (int*)(bstart + 16);

  int nblk = (n + 255) / 256;
  pass_keys<<<nblk, 256, 0, stream>>>(pts, batch, n, keys, bstart);
  hist_all<<<256, 1024, 0, stream>>>(bstart, keys, n, rep2s, rep4s, rep1s);
  scanA<<<NB1, 256, 0, stream>>>(rep2s, rep4s, rep1s, bits, blockSums);
  scanC<<<NB1, 256, 0, stream>>>(bits, blockSums, pairs);
  epilogue<<<NBLK_INV8 + NBLK_COORS + NBLK_TAIL, 256, 0, stream>>>(n, pairs, keys, out);
}